// Round 7
// baseline (392.025 us; speedup 1.0000x reference)
//
#include <hip/hip_runtime.h>
#include <math.h>

#define BATCH 2
#define SEQ 2048
#define DMODEL 1024
#define HEADS 16
#define HSIZE 64
#define FREQS 256
#define NH 1024
#define QKVN 3072

typedef __bf16 bf16;
typedef __bf16 bf16x8 __attribute__((ext_vector_type(8)));
typedef float f32x4 __attribute__((ext_vector_type(4)));

// attn dispatch table: 24 (qc,half) units sorted by descending tile count
__constant__ int c_qc[24] = {15,15,7,14,14,13,13,6,12,12,5,11,11,10,10,4,9,9,8,8,3,2,1,0};
__constant__ int c_hh[24] = { 0, 1,0, 0, 1, 0, 1,0, 0, 1,0, 0, 1, 0, 1,0,0,1,0,1,0,0,0,0};

static __device__ __forceinline__ unsigned short bf16_bits(float v) {
    bf16 b = (bf16)v; return __builtin_bit_cast(unsigned short, b);
}

// async global->LDS, 16 bytes per lane; LDS dest = wave-uniform base + lane*16
static __device__ __forceinline__ void gload16(const void* g, void* l) {
    __builtin_amdgcn_global_load_lds(
        (const __attribute__((address_space(1))) unsigned int*)g,
        (__attribute__((address_space(3))) unsigned int*)l, 16, 0, 0);
}

// ---------------------------------------------------------------------------
// Merged prep: input cast, sins table, three weight transposes. One launch.
//   [0,4096)       cast input
//   [4096,4128)    sins (1 fp64 pow per thread, fp32 sincos after reduction)
//   [4128,7200)    transpose qkv_w (1024x3072)
//   [7200,8224)    transpose out_kernel (1024x1024)
//   [8224,8480)    transpose positional (256x1024)
// ---------------------------------------------------------------------------
__global__ __launch_bounds__(256) void prep_kernel(
    const float* __restrict__ inp, const float* __restrict__ qkv_w,
    const float* __restrict__ out_kernel, const float* __restrict__ positional,
    bf16* __restrict__ a_bf, bf16* __restrict__ wt_qkv,
    bf16* __restrict__ wt_out, bf16* __restrict__ wt_pos,
    bf16* __restrict__ sins_bf)
{
    __shared__ float tile[32][33];
    const int id = blockIdx.x, t = threadIdx.x;

    if (id < 4096) {            // input cast
        int i = id * 256 + t;
        float4 v = ((const float4*)inp)[i];
        ushort4 o;
        o.x = bf16_bits(v.x); o.y = bf16_bits(v.y);
        o.z = bf16_bits(v.z); o.w = bf16_bits(v.w);
        ((ushort4*)a_bf)[i] = o;
        return;
    }
    if (id < 4128) {            // sins: thread t = freq f, 64 s-rows per block
        const int br = id - 4096;
        const int f = t;
        double e = -(double)((f >> 1) << 1) / (double)FREQS;
        double invf = pow(10000.0, e);
        const double twopi = 6.283185307179586;
        const double inv2pi = 0.15915494309189535;
        for (int j = 0; j < 64; ++j) {
            int s = br * 64 + j;
            double ang = (double)s * invf;
            double r = ang - floor(ang * inv2pi) * twopi;
            float rf = (float)r;
            float v = (f & 1) ? cosf(rf) : sinf(rf);
            sins_bf[s * 256 + f] = (bf16)(1.41421356f * v);
        }
        return;
    }
    int id2 = id - 4128;
    const float* src; bf16* dst; int R, C, c0, r0;
    if (id2 < 3072) {
        src = qkv_w; dst = wt_qkv; R = 1024; C = 3072;
        c0 = (id2 % 96) * 32; r0 = (id2 / 96) * 32;
    } else if (id2 < 4096) {
        id2 -= 3072;
        src = out_kernel; dst = wt_out; R = 1024; C = 1024;
        c0 = (id2 & 31) * 32; r0 = (id2 >> 5) * 32;
    } else {
        id2 -= 4096;
        src = positional; dst = wt_pos; R = 256; C = 1024;
        c0 = (id2 & 31) * 32; r0 = (id2 >> 5) * 32;
    }
    const int tx = t & 31, ty = t >> 5;
#pragma unroll
    for (int i = 0; i < 4; i++)
        tile[ty + i * 8][tx] = src[(size_t)(r0 + ty + i * 8) * C + c0 + tx];
    __syncthreads();
#pragma unroll
    for (int i = 0; i < 4; i++)
        dst[(size_t)(c0 + ty + i * 8) * R + r0 + tx] = (bf16)tile[tx][ty + i * 8];
}

// ---------------------------------------------------------------------------
// Pipelined bf16 MFMA GEMM (unchanged structure from round 6).
// EPI 0: out-proj fp32 = acc*alpha + bias[col]
// EPI 1: merged QKV+emb: x<24 -> QKV (Q plain *0.125*log2e, K swizzled,
//        V swapped->Vt swizzled); x>=24 -> embT[head][d][h] PLAIN layout
// ---------------------------------------------------------------------------
template<int EPI>
__global__ __launch_bounds__(256) void mfma_gemm(
    const bf16* __restrict__ A, const bf16* __restrict__ Bt,
    int K, float alpha, const float* __restrict__ bias,
    float* __restrict__ outf, bf16* __restrict__ ob0, bf16* __restrict__ ob1,
    bf16* __restrict__ ob2,
    const bf16* __restrict__ A2, const bf16* __restrict__ Bt2,
    bf16* __restrict__ ob3, float alpha2)
{
    __shared__ __align__(16) bf16 Atile[2][128 * 32];
    __shared__ __align__(16) bf16 Btile[2][128 * 32];

    const int t    = threadIdx.x;
    const int lane = t & 63;
    const int w    = t >> 6;
    const int quad = lane >> 4;
    const int l16  = lane & 15;
    const int wm   = (w >> 1) * 64;
    const int wn   = (w & 1) * 64;

    bool embp = false;
    int m0 = blockIdx.y * 128, n0 = blockIdx.x * 128, Kl = K;
    const bf16* Ap = A; const bf16* Btp = Bt; float al = alpha;
    if constexpr (EPI == 1) {
        if (blockIdx.x >= 24) {
            if (blockIdx.y >= 16) return;
            embp = true;
            n0 = (blockIdx.x - 24) * 128;
            Kl = FREQS; Ap = A2; Btp = Bt2; al = alpha2;
        }
    }
    const bool swapv = (EPI == 1) && !embp && (n0 >= 2048);

    const int rS = t >> 2;
    const int cS = (t & 3) ^ ((rS >> 1) & 3);
    const bf16* ag0 = Ap  + (size_t)(m0 + rS) * Kl + cS * 8;
    const bf16* ag1 = ag0 + (size_t)64 * Kl;
    const bf16* bg0 = Btp + (size_t)(n0 + rS) * Kl + cS * 8;
    const bf16* bg1 = bg0 + (size_t)64 * Kl;

    int aoff[4], boff[4];
#pragma unroll
    for (int mi = 0; mi < 4; ++mi) {
        int r = wm + mi * 16 + l16;
        aoff[mi] = r * 32 + ((quad ^ ((r >> 1) & 3)) * 8);
    }
#pragma unroll
    for (int ni = 0; ni < 4; ++ni) {
        int r = wn + ni * 16 + l16;
        boff[ni] = r * 32 + ((quad ^ ((r >> 1) & 3)) * 8);
    }

    gload16(ag0, (char*)Atile[0] + t * 16);
    gload16(ag1, (char*)Atile[0] + 4096 + t * 16);
    gload16(bg0, (char*)Btile[0] + t * 16);
    gload16(bg1, (char*)Btile[0] + 4096 + t * 16);

    const int nK = Kl >> 5;
    f32x4 acc[4][4] = {};

    for (int kk = 0; kk < nK; ++kk) {
        __syncthreads();
        if (kk + 1 < nK) {
            ag0 += 32; ag1 += 32; bg0 += 32; bg1 += 32;
            char* ad = (char*)Atile[(kk + 1) & 1];
            char* bd = (char*)Btile[(kk + 1) & 1];
            gload16(ag0, ad + t * 16); gload16(ag1, ad + 4096 + t * 16);
            gload16(bg0, bd + t * 16); gload16(bg1, bd + 4096 + t * 16);
        }
        const bf16* ab = Atile[kk & 1];
        const bf16* bb = Btile[kk & 1];
        bf16x8 af[4], bfr[4];
#pragma unroll
        for (int mi = 0; mi < 4; ++mi) af[mi] = *(const bf16x8*)(ab + aoff[mi]);
#pragma unroll
        for (int ni = 0; ni < 4; ++ni) bfr[ni] = *(const bf16x8*)(bb + boff[ni]);

        if (!swapv) {
#pragma unroll
            for (int mi = 0; mi < 4; ++mi)
#pragma unroll
                for (int ni = 0; ni < 4; ++ni)
                    acc[mi][ni] = __builtin_amdgcn_mfma_f32_16x16x32_bf16(
                        af[mi], bfr[ni], acc[mi][ni], 0, 0, 0);
        } else {
#pragma unroll
            for (int mi = 0; mi < 4; ++mi)
#pragma unroll
                for (int ni = 0; ni < 4; ++ni)
                    acc[mi][ni] = __builtin_amdgcn_mfma_f32_16x16x32_bf16(
                        bfr[ni], af[mi], acc[mi][ni], 0, 0, 0);
        }
    }

    if constexpr (EPI == 0) {
#pragma unroll
        for (int mi = 0; mi < 4; ++mi)
#pragma unroll
            for (int ni = 0; ni < 4; ++ni) {
                int col = n0 + wn + ni * 16 + l16;
                float bb = bias[col];
#pragma unroll
                for (int rg = 0; rg < 4; ++rg) {
                    int row = m0 + wm + mi * 16 + quad * 4 + rg;
                    outf[(size_t)row * NH + col] = acc[mi][ni][rg] * al + bb;
                }
            }
    } else {
        if (embp) {  // embT[head][d][h] PLAIN (direct-global frag reads)
#pragma unroll
            for (int mi = 0; mi < 4; ++mi)
#pragma unroll
                for (int ni = 0; ni < 4; ++ni) {
                    int col = n0 + wn + ni * 16 + l16;
                    int head = col >> 6, h = col & 63;
#pragma unroll
                    for (int rg = 0; rg < 4; ++rg) {
                        int d = m0 + wm + mi * 16 + quad * 4 + rg;
                        ob3[((size_t)(head * SEQ + d)) * 64 + h] =
                            (bf16)(acc[mi][ni][rg] * al);
                    }
                }
        } else if (n0 >= 2048) {
#pragma unroll
            for (int mi = 0; mi < 4; ++mi)
#pragma unroll
                for (int ni = 0; ni < 4; ++ni) {
                    int mcol = m0 + wm + mi * 16 + l16;
                    int bb = mcol >> 11, s = mcol & 2047;
#pragma unroll
                    for (int rg = 0; rg < 4; ++rg) {
                        int hg = n0 + wn + ni * 16 + quad * 4 + rg;
                        int head = (hg & 1023) >> 6, h = hg & 63;
                        int ss = s ^ ((h & 7) << 3);
                        ob2[((size_t)((bb * 16 + head) * 64 + h)) * SEQ + ss] =
                            (bf16)(acc[mi][ni][rg] * al);
                    }
                }
        } else {
            const int whichk = (n0 >= 1024);
#pragma unroll
            for (int mi = 0; mi < 4; ++mi)
#pragma unroll
                for (int ni = 0; ni < 4; ++ni) {
                    int cg   = (n0 + wn + ni * 16 + l16) & 1023;
                    int head = cg >> 6, h = cg & 63;
                    float qbv = whichk ? 0.0f : bias[cg];
#pragma unroll
                    for (int rg = 0; rg < 4; ++rg) {
                        int row = m0 + wm + mi * 16 + quad * 4 + rg;
                        int bb = row >> 11, s = row & 2047;
                        float v = acc[mi][ni][rg] * al;
                        if (whichk) {
                            int hs = h ^ ((s & 7) << 3);
                            ob1[((size_t)((bb * 16 + head) * SEQ + s)) * 64 + hs] = (bf16)v;
                        } else {
                            // fold 0.125 * log2(e) so scores use exp2
                            ob0[((size_t)((bb * 16 + head) * SEQ + s)) * 64 + h] =
                                (bf16)((v + qbv) * 0.18033688f);
                        }
                    }
                }
        }
    }
}

// ---------------------------------------------------------------------------
// MFMA flash attention v6: 128-row Q tile, K/V dbuf (LDS 41 KB -> 3 blocks/CU),
// E fragments DIRECT from global (plain embT), k-split x2 for qc>=8 with
// additive no-max partials, work-sorted dispatch table, exp2 softmax.
// Grid: (32 bn, 24 work units).
// ---------------------------------------------------------------------------
__global__ __launch_bounds__(256, 3) void attn_kernel(
    const bf16* __restrict__ Qb, const bf16* __restrict__ Kb,
    const bf16* __restrict__ Vtb, const bf16* __restrict__ Eb,
    bf16* __restrict__ o, float* __restrict__ pO, float* __restrict__ pl)
{
    __shared__ __align__(16) bf16 Ks[2][4096];
    __shared__ __align__(16) bf16 Vts[2][4096];
    __shared__ __align__(16) bf16 PS[4][16][72];

    const int t    = threadIdx.x;
    const int lane = t & 63;
    const int w    = t >> 6;
    const int quad = lane >> 4;
    const int l16  = lane & 15;

    const int bx = blockIdx.x;
    const int b  = bx >> 4, n = bx & 15;
    const int qc = c_qc[blockIdx.y];
    const int hh = c_hh[blockIdx.y];
    const bool split = qc >= 8;
    const int ks = hh ? qc + 1 : 0;
    const int ke = split ? (hh ? 2 * qc + 2 : qc + 1) : 2 * qc + 2;
    const int q0 = qc * 128;
    const int qw0 = q0 + 16 * w;
    const int qw1 = qw0 + 64;

    const bf16* __restrict__ Qp = Qb  + (size_t)bx * SEQ * 64;
    const bf16* __restrict__ Kp = Kb  + (size_t)bx * SEQ * 64;
    const bf16* __restrict__ Vp = Vtb + (size_t)bx * SEQ * 64;
    const bf16* __restrict__ Ep = Eb  + (size_t)n  * SEQ * 64;

    const int key8 = (l16 & 7) << 3;
    const int ec0  = ((quad * 8) ^ key8) * 2;
    const int ec1  = ((32 + quad * 8) ^ key8) * 2;

    bf16x8 qf[2][2];
    qf[0][0] = *(const bf16x8*)(Qp + (size_t)(qw0 + l16) * 64 + quad * 8);
    qf[0][1] = *(const bf16x8*)(Qp + (size_t)(qw0 + l16) * 64 + 32 + quad * 8);
    qf[1][0] = *(const bf16x8*)(Qp + (size_t)(qw1 + l16) * 64 + quad * 8);
    qf[1][1] = *(const bf16x8*)(Qp + (size_t)(qw1 + l16) * 64 + 32 + quad * 8);

    int dsta[4];
    bool condp[4];
#pragma unroll
    for (int rg = 0; rg < 4; ++rg) {
        int rr   = quad * 4 + rg;
        int l16c = (rr + 15 - l16) & 15;
        dsta[rg]  = ((lane & 48) + l16c) << 2;
        condp[rg] = rr > l16c;
    }

    f32x4 O[2][4] = {};
    float lsum[2][4] = {};

    // preload K/V tile ks into buffer (ks&1)
    {
        char* kd = (char*)Ks[ks & 1];
        char* vd = (char*)Vts[ks & 1];
        const bf16* ksrc = Kp + ks * 4096;
        gload16(ksrc + t * 8,        kd + t * 16);
        gload16(ksrc + 2048 + t * 8, kd + 4096 + t * 16);
        gload16(Vp + (size_t)(t >> 3) * SEQ + ks * 64 + (t & 7) * 8,        vd + t * 16);
        gload16(Vp + (size_t)((t >> 3) + 32) * SEQ + ks * 64 + (t & 7) * 8, vd + 4096 + t * 16);
    }

    for (int kt = ks; kt < ke; ++kt) {
        const int k0 = kt * 64;
        __syncthreads();

        const int nt = kt + 1;
        if (nt < ke) {
            char* kd = (char*)Ks[nt & 1];
            char* vd = (char*)Vts[nt & 1];
            const bf16* ksrc = Kp + nt * 4096;
            gload16(ksrc + t * 8,        kd + t * 16);
            gload16(ksrc + 2048 + t * 8, kd + 4096 + t * 16);
            gload16(Vp + (size_t)(t >> 3) * SEQ + nt * 64 + (t & 7) * 8,        vd + t * 16);
            gload16(Vp + (size_t)((t >> 3) + 32) * SEQ + nt * 64 + (t & 7) * 8, vd + 4096 + t * 16);
        }

        const char* kb = (const char*)Ks[kt & 1];
        const char* vb = (const char*)Vts[kt & 1];
        bf16x8 kf[4][2], vf[4][2];
#pragma unroll
        for (int j = 0; j < 4; ++j) {
            const char* kp = kb + (j * 16 + l16) * 128;
            kf[j][0] = *(const bf16x8*)(kp + ec0);
            kf[j][1] = *(const bf16x8*)(kp + ec1);
            const char* vp = vb + (j * 16 + l16) * 128;
            vf[j][0] = *(const bf16x8*)(vp + ec0);
            vf[j][1] = *(const bf16x8*)(vp + ec1);
        }

#pragma unroll
        for (int c = 0; c < 2; ++c) {
            if (c == 0 && k0 >= q0 + 64) continue;   // chunk0 fully masked
            const int qwc = c ? qw1 : qw0;

            // E band direct from global: d = qwc - k0 - 63 + 16jj + l16
            const bf16* eb = Ep + (ptrdiff_t)((qwc - k0 - 63 + l16) * 64) + quad * 8;
            f32x4 pa[5];
#pragma unroll
            for (int jj = 0; jj < 5; ++jj) {
                bf16x8 e0 = *(const bf16x8*)(eb + jj * 1024);
                bf16x8 e1 = *(const bf16x8*)(eb + jj * 1024 + 32);
                f32x4 a = {0, 0, 0, 0};
                a = __builtin_amdgcn_mfma_f32_16x16x32_bf16(qf[c][1], e1, a, 0, 0, 0);
                a = __builtin_amdgcn_mfma_f32_16x16x32_bf16(qf[c][0], e0, a, 0, 0, 0);
                pa[jj] = a;
            }

            f32x4 S[4];
#pragma unroll
            for (int j = 0; j < 4; ++j) {
                f32x4 a = {0, 0, 0, 0};
                a = __builtin_amdgcn_mfma_f32_16x16x32_bf16(qf[c][1], kf[j][1], a, 0, 0, 0);
                a = __builtin_amdgcn_mfma_f32_16x16x32_bf16(qf[c][0], kf[j][0], a, 0, 0, 0);
                S[j] = a;
            }

#pragma unroll
            for (int j = 0; j < 4; ++j) {
#pragma unroll
                for (int rg = 0; rg < 4; ++rg) {
                    float vsel = condp[rg] ? pa[4 - j][rg] : pa[3 - j][rg];
                    int pv = __builtin_amdgcn_ds_permute(dsta[rg], __float_as_int(vsel));
                    float sv = S[j][rg] + __int_as_float(pv);
                    bool valid = (k0 + j * 16 + l16) <= (qwc + quad * 4 + rg);
                    S[j][rg] = valid ? exp2f(sv) : 0.0f;
                }
            }
#pragma unroll
            for (int rg = 0; rg < 4; ++rg)
                lsum[c][rg] += S[0][rg] + S[1][rg] + S[2][rg] + S[3][rg];

#pragma unroll
            for (int j = 0; j < 4; ++j)
#pragma unroll
                for (int rg = 0; rg < 4; ++rg)
                    PS[w][quad * 4 + rg][j * 16 + l16] = (bf16)S[j][rg];
            bf16x8 pf0 = *(const bf16x8*)(&PS[w][l16][quad * 8]);
            bf16x8 pf1 = *(const bf16x8*)(&PS[w][l16][32 + quad * 8]);

#pragma unroll
            for (int j4 = 0; j4 < 4; ++j4) {
                O[c][j4] = __builtin_amdgcn_mfma_f32_16x16x32_bf16(pf1, vf[j4][1], O[c][j4], 0, 0, 0);
                O[c][j4] = __builtin_amdgcn_mfma_f32_16x16x32_bf16(pf0, vf[j4][0], O[c][j4], 0, 0, 0);
            }
        }
    }

    if (!split) {
        // normalize + write bf16 obuf (rows < 1024)
#pragma unroll
        for (int c = 0; c < 2; ++c) {
#pragma unroll
            for (int rg = 0; rg < 4; ++rg) {
                float s = lsum[c][rg];
                s += __shfl_xor(s, 1);
                s += __shfl_xor(s, 2);
                s += __shfl_xor(s, 4);
                s += __shfl_xor(s, 8);
                float inv = 1.0f / s;
                int q = (c ? qw1 : qw0) + quad * 4 + rg;
                size_t ro = ((size_t)(b * SEQ + q)) * NH + n * 64;
                o[ro +  0 + l16] = (bf16)(O[c][0][rg] * inv);
                o[ro + 16 + l16] = (bf16)(O[c][1][rg] * inv);
                o[ro + 32 + l16] = (bf16)(O[c][2][rg] * inv);
                o[ro + 48 + l16] = (bf16)(O[c][3][rg] * inv);
            }
        }
    } else {
        // unnormalized fp32 partials + row-sums (additive across halves)
        const size_t pbase = (((size_t)(hh * 2 + b) * 16 + n) * 1024 + (size_t)(qc - 8) * 128);
#pragma unroll
        for (int c = 0; c < 2; ++c) {
#pragma unroll
            for (int rg = 0; rg < 4; ++rg) {
                float s = lsum[c][rg];
                s += __shfl_xor(s, 1);
                s += __shfl_xor(s, 2);
                s += __shfl_xor(s, 4);
                s += __shfl_xor(s, 8);
                int rloc = 16 * w + 64 * c + quad * 4 + rg;
                if (l16 == 0) pl[pbase + rloc] = s;
                float* po = pO + (pbase + rloc) * 64;
                po[ 0 + l16] = O[c][0][rg];
                po[16 + l16] = O[c][1][rg];
                po[32 + l16] = O[c][2][rg];
                po[48 + l16] = O[c][3][rg];
            }
        }
    }
}

// ---------------------------------------------------------------------------
// Combine the two k-split halves for rows q in [1024,2048): O=(Oa+Ob)/(la+lb)
// ---------------------------------------------------------------------------
__global__ __launch_bounds__(256) void combine_kernel(
    const float* __restrict__ pO, const float* __restrict__ pl,
    bf16* __restrict__ o)
{
    const int e = blockIdx.x * 1024 + threadIdx.x * 4;
    const int col = e & 63;
    const int r   = (e >> 6) & 1023;
    const int n   = (e >> 16) & 15;
    const int b   = e >> 20;
    const size_t i0 = (size_t)(b * 16 + n) * 1024 + r;
    float4 va = *(const float4*)(pO + i0 * 64 + col);
    float4 vb = *(const float4*)(pO + (size_t)2097152 + i0 * 64 + col);
    float inv = 1.0f / (pl[i0] + pl[32768 + i0]);
    ushort4 ov;
    ov.x = bf16_bits((va.x + vb.x) * inv);
    ov.y = bf16_bits((va.y + vb.y) * inv);
    ov.z = bf16_bits((va.z + vb.z) * inv);
    ov.w = bf16_bits((va.w + vb.w) * inv);
    *(ushort4*)((unsigned short*)o +
                ((size_t)(b * SEQ + 1024 + r)) * NH + n * 64 + col) = ov;
}

// ---------------------------------------------------------------------------
extern "C" void kernel_launch(void* const* d_in, const int* in_sizes, int n_in,
                              void* d_out, int out_size, void* d_ws, size_t ws_size,
                              hipStream_t stream) {
    const float* inp        = (const float*)d_in[0];
    const float* qkv_w      = (const float*)d_in[1];
    const float* q_bias     = (const float*)d_in[2];
    const float* positional = (const float*)d_in[3];
    const float* out_kernel = (const float*)d_in[4];
    const float* out_bias   = (const float*)d_in[5];

    char* p = (char*)d_ws;
    auto alloc = [&](size_t bytes) {
        char* q = p; p += (bytes + 255) & ~(size_t)255; return q;
    };
    bf16* qbuf    = (bf16*)alloc((size_t)BATCH * HEADS * SEQ * HSIZE * 2);
    bf16* kbuf    = (bf16*)alloc((size_t)BATCH * HEADS * SEQ * HSIZE * 2);
    bf16* vtbuf   = (bf16*)alloc((size_t)BATCH * HEADS * SEQ * HSIZE * 2);
    bf16* embT    = (bf16*)alloc((size_t)HEADS * SEQ * HSIZE * 2);  // after vtbuf (negative-d slack)
    bf16* sins_bf = (bf16*)alloc((size_t)SEQ * FREQS * 2);          // after embT (d>=2048 slack)
    bf16* obuf    = (bf16*)alloc((size_t)BATCH * SEQ * NH * 2);
    bf16* a_bf    = (bf16*)alloc((size_t)BATCH * SEQ * DMODEL * 2);
    bf16* wt_qkv  = (bf16*)alloc((size_t)QKVN * DMODEL * 2);
    bf16* wt_out  = (bf16*)alloc((size_t)NH * DMODEL * 2);
    bf16* wt_pos  = (bf16*)alloc((size_t)NH * FREQS * 2);
    float* pO     = (float*)alloc((size_t)2 * 2 * 16 * 1024 * 64 * 4);  // 16.8 MB
    float* pl     = (float*)alloc((size_t)2 * 2 * 16 * 1024 * 4);       // 512 KB

    const float qkv_scale = (float)pow(3.0 * DMODEL * HSIZE * HEADS, -0.25);
    const float emb_scale = 0.0625f;   // 256^-0.5
    const float out_scale = 0.03125f;  // (1024*1024)^-0.25

    // 1. merged prep
    prep_kernel<<<8480, 256, 0, stream>>>(
        inp, qkv_w, out_kernel, positional, a_bf, wt_qkv, wt_out, wt_pos, sins_bf);

    // 2. merged QKV projection + emb GEMM
    mfma_gemm<1><<<dim3(32, 32), 256, 0, stream>>>(
        a_bf, wt_qkv, DMODEL, qkv_scale, q_bias, nullptr, qbuf, kbuf, vtbuf,
        sins_bf, wt_pos, embT, emb_scale);

    // 3. flash attention (768 work-sorted blocks, k-split for qc>=8)
    attn_kernel<<<dim3(32, 24), 256, 0, stream>>>(
        qbuf, kbuf, vtbuf, embT, obuf, pO, pl);

    // 4. combine split halves (rows 1024..2047)
    combine_kernel<<<2048, 256, 0, stream>>>(pO, pl, obuf);

    // 5. output projection (fp32 out)
    mfma_gemm<0><<<dim3(8, 32), 256, 0, stream>>>(
        obuf, wt_out, DMODEL, out_scale, out_bias, (float*)d_out,
        nullptr, nullptr, nullptr, nullptr, nullptr, nullptr, 0.0f);
}

// Round 8
// 266.378 us; speedup vs baseline: 1.4717x; 1.4717x over previous
//
#include <hip/hip_runtime.h>
#include <math.h>

#define BATCH 2
#define SEQ 2048
#define DMODEL 1024
#define HEADS 16
#define HSIZE 64
#define FREQS 256
#define NH 1024
#define QKVN 3072

typedef __bf16 bf16;
typedef __bf16 bf16x8 __attribute__((ext_vector_type(8)));
typedef float f32x4 __attribute__((ext_vector_type(4)));

static __device__ __forceinline__ unsigned short bf16_bits(float v) {
    bf16 b = (bf16)v; return __builtin_bit_cast(unsigned short, b);
}

// async global->LDS, 16 bytes per lane; LDS dest = wave-uniform base + lane*16
static __device__ __forceinline__ void gload16(const void* g, void* l) {
    __builtin_amdgcn_global_load_lds(
        (const __attribute__((address_space(1))) unsigned int*)g,
        (__attribute__((address_space(3))) unsigned int*)l, 16, 0, 0);
}

// ---------------------------------------------------------------------------
// Merged prep: input cast, sins table, three weight transposes. One launch.
// ---------------------------------------------------------------------------
__global__ __launch_bounds__(256) void prep_kernel(
    const float* __restrict__ inp, const float* __restrict__ qkv_w,
    const float* __restrict__ out_kernel, const float* __restrict__ positional,
    bf16* __restrict__ a_bf, bf16* __restrict__ wt_qkv,
    bf16* __restrict__ wt_out, bf16* __restrict__ wt_pos,
    bf16* __restrict__ sins_bf)
{
    __shared__ float tile[32][33];
    const int id = blockIdx.x, t = threadIdx.x;

    if (id < 4096) {            // input cast
        int i = id * 256 + t;
        float4 v = ((const float4*)inp)[i];
        ushort4 o;
        o.x = bf16_bits(v.x); o.y = bf16_bits(v.y);
        o.z = bf16_bits(v.z); o.w = bf16_bits(v.w);
        ((ushort4*)a_bf)[i] = o;
        return;
    }
    if (id < 4128) {            // sins: thread t = freq f, 64 s-rows per block
        const int br = id - 4096;
        const int f = t;
        double e = -(double)((f >> 1) << 1) / (double)FREQS;
        double invf = pow(10000.0, e);
        const double twopi = 6.283185307179586;
        const double inv2pi = 0.15915494309189535;
        for (int j = 0; j < 64; ++j) {
            int s = br * 64 + j;
            double ang = (double)s * invf;
            double r = ang - floor(ang * inv2pi) * twopi;
            float rf = (float)r;
            float v = (f & 1) ? cosf(rf) : sinf(rf);
            sins_bf[s * 256 + f] = (bf16)(1.41421356f * v);
        }
        return;
    }
    int id2 = id - 4128;
    const float* src; bf16* dst; int R, C, c0, r0;
    if (id2 < 3072) {
        src = qkv_w; dst = wt_qkv; R = 1024; C = 3072;
        c0 = (id2 % 96) * 32; r0 = (id2 / 96) * 32;
    } else if (id2 < 4096) {
        id2 -= 3072;
        src = out_kernel; dst = wt_out; R = 1024; C = 1024;
        c0 = (id2 & 31) * 32; r0 = (id2 >> 5) * 32;
    } else {
        id2 -= 4096;
        src = positional; dst = wt_pos; R = 256; C = 1024;
        c0 = (id2 & 31) * 32; r0 = (id2 >> 5) * 32;
    }
    const int tx = t & 31, ty = t >> 5;
#pragma unroll
    for (int i = 0; i < 4; i++)
        tile[ty + i * 8][tx] = src[(size_t)(r0 + ty + i * 8) * C + c0 + tx];
    __syncthreads();
#pragma unroll
    for (int i = 0; i < 4; i++)
        dst[(size_t)(c0 + ty + i * 8) * R + r0 + tx] = (bf16)tile[tx][ty + i * 8];
}

// ---------------------------------------------------------------------------
// Pipelined bf16 MFMA GEMM: C[M][N] = A[M][K] @ Bt[N][K]^T, 128x128 tile,
// BK=32, double-buffered LDS, one barrier per K-iter.
// EPI 0: out-proj fp32 = acc*alpha + bias[col]
// EPI 1: merged QKV+emb: x<24 -> QKV (Q plain *0.125*log2e, K swizzled,
//        V swapped->Vt swizzled); x>=24 -> embT[head][d][h'] swizzled
// ---------------------------------------------------------------------------
template<int EPI>
__global__ __launch_bounds__(256) void mfma_gemm(
    const bf16* __restrict__ A, const bf16* __restrict__ Bt,
    int K, float alpha, const float* __restrict__ bias,
    float* __restrict__ outf, bf16* __restrict__ ob0, bf16* __restrict__ ob1,
    bf16* __restrict__ ob2,
    const bf16* __restrict__ A2, const bf16* __restrict__ Bt2,
    bf16* __restrict__ ob3, float alpha2)
{
    __shared__ __align__(16) bf16 Atile[2][128 * 32];
    __shared__ __align__(16) bf16 Btile[2][128 * 32];

    const int t    = threadIdx.x;
    const int lane = t & 63;
    const int w    = t >> 6;
    const int quad = lane >> 4;
    const int l16  = lane & 15;
    const int wm   = (w >> 1) * 64;
    const int wn   = (w & 1) * 64;

    bool embp = false;
    int m0 = blockIdx.y * 128, n0 = blockIdx.x * 128, Kl = K;
    const bf16* Ap = A; const bf16* Btp = Bt; float al = alpha;
    if constexpr (EPI == 1) {
        if (blockIdx.x >= 24) {
            if (blockIdx.y >= 16) return;
            embp = true;
            n0 = (blockIdx.x - 24) * 128;
            Kl = FREQS; Ap = A2; Btp = Bt2; al = alpha2;
        }
    }
    const bool swapv = (EPI == 1) && !embp && (n0 >= 2048);

    const int rS = t >> 2;
    const int cS = (t & 3) ^ ((rS >> 1) & 3);
    const bf16* ag0 = Ap  + (size_t)(m0 + rS) * Kl + cS * 8;
    const bf16* ag1 = ag0 + (size_t)64 * Kl;
    const bf16* bg0 = Btp + (size_t)(n0 + rS) * Kl + cS * 8;
    const bf16* bg1 = bg0 + (size_t)64 * Kl;

    int aoff[4], boff[4];
#pragma unroll
    for (int mi = 0; mi < 4; ++mi) {
        int r = wm + mi * 16 + l16;
        aoff[mi] = r * 32 + ((quad ^ ((r >> 1) & 3)) * 8);
    }
#pragma unroll
    for (int ni = 0; ni < 4; ++ni) {
        int r = wn + ni * 16 + l16;
        boff[ni] = r * 32 + ((quad ^ ((r >> 1) & 3)) * 8);
    }

    gload16(ag0, (char*)Atile[0] + t * 16);
    gload16(ag1, (char*)Atile[0] + 4096 + t * 16);
    gload16(bg0, (char*)Btile[0] + t * 16);
    gload16(bg1, (char*)Btile[0] + 4096 + t * 16);

    const int nK = Kl >> 5;
    f32x4 acc[4][4] = {};

    for (int kk = 0; kk < nK; ++kk) {
        __syncthreads();
        if (kk + 1 < nK) {
            ag0 += 32; ag1 += 32; bg0 += 32; bg1 += 32;
            char* ad = (char*)Atile[(kk + 1) & 1];
            char* bd = (char*)Btile[(kk + 1) & 1];
            gload16(ag0, ad + t * 16); gload16(ag1, ad + 4096 + t * 16);
            gload16(bg0, bd + t * 16); gload16(bg1, bd + 4096 + t * 16);
        }
        const bf16* ab = Atile[kk & 1];
        const bf16* bb = Btile[kk & 1];
        bf16x8 af[4], bfr[4];
#pragma unroll
        for (int mi = 0; mi < 4; ++mi) af[mi] = *(const bf16x8*)(ab + aoff[mi]);
#pragma unroll
        for (int ni = 0; ni < 4; ++ni) bfr[ni] = *(const bf16x8*)(bb + boff[ni]);

        if (!swapv) {
#pragma unroll
            for (int mi = 0; mi < 4; ++mi)
#pragma unroll
                for (int ni = 0; ni < 4; ++ni)
                    acc[mi][ni] = __builtin_amdgcn_mfma_f32_16x16x32_bf16(
                        af[mi], bfr[ni], acc[mi][ni], 0, 0, 0);
        } else {
#pragma unroll
            for (int mi = 0; mi < 4; ++mi)
#pragma unroll
                for (int ni = 0; ni < 4; ++ni)
                    acc[mi][ni] = __builtin_amdgcn_mfma_f32_16x16x32_bf16(
                        bfr[ni], af[mi], acc[mi][ni], 0, 0, 0);
        }
    }

    if constexpr (EPI == 0) {
#pragma unroll
        for (int mi = 0; mi < 4; ++mi)
#pragma unroll
            for (int ni = 0; ni < 4; ++ni) {
                int col = n0 + wn + ni * 16 + l16;
                float bb = bias[col];
#pragma unroll
                for (int rg = 0; rg < 4; ++rg) {
                    int row = m0 + wm + mi * 16 + quad * 4 + rg;
                    outf[(size_t)row * NH + col] = acc[mi][ni][rg] * al + bb;
                }
            }
    } else {
        if (embp) {  // embT[head][d][h'] chunk-swizzled by (d+63)&7
#pragma unroll
            for (int mi = 0; mi < 4; ++mi)
#pragma unroll
                for (int ni = 0; ni < 4; ++ni) {
                    int col = n0 + wn + ni * 16 + l16;
                    int head = col >> 6, h = col & 63;
#pragma unroll
                    for (int rg = 0; rg < 4; ++rg) {
                        int d = m0 + wm + mi * 16 + quad * 4 + rg;
                        int hs = h ^ (((d + 63) & 7) << 3);
                        ob3[((size_t)(head * SEQ + d)) * 64 + hs] =
                            (bf16)(acc[mi][ni][rg] * al);
                    }
                }
        } else if (n0 >= 2048) {
#pragma unroll
            for (int mi = 0; mi < 4; ++mi)
#pragma unroll
                for (int ni = 0; ni < 4; ++ni) {
                    int mcol = m0 + wm + mi * 16 + l16;
                    int bb = mcol >> 11, s = mcol & 2047;
#pragma unroll
                    for (int rg = 0; rg < 4; ++rg) {
                        int hg = n0 + wn + ni * 16 + quad * 4 + rg;
                        int head = (hg & 1023) >> 6, h = hg & 63;
                        int ss = s ^ ((h & 7) << 3);
                        ob2[((size_t)((bb * 16 + head) * 64 + h)) * SEQ + ss] =
                            (bf16)(acc[mi][ni][rg] * al);
                    }
                }
        } else {
            const int whichk = (n0 >= 1024);
#pragma unroll
            for (int mi = 0; mi < 4; ++mi)
#pragma unroll
                for (int ni = 0; ni < 4; ++ni) {
                    int cg   = (n0 + wn + ni * 16 + l16) & 1023;
                    int head = cg >> 6, h = cg & 63;
                    float qbv = whichk ? 0.0f : bias[cg];
#pragma unroll
                    for (int rg = 0; rg < 4; ++rg) {
                        int row = m0 + wm + mi * 16 + quad * 4 + rg;
                        int bb = row >> 11, s = row & 2047;
                        float v = acc[mi][ni][rg] * al;
                        if (whichk) {
                            int hs = h ^ ((s & 7) << 3);
                            ob1[((size_t)((bb * 16 + head) * SEQ + s)) * 64 + hs] = (bf16)v;
                        } else {
                            // fold 0.125 * log2(e): softmax uses exp2
                            ob0[((size_t)((bb * 16 + head) * SEQ + s)) * 64 + h] =
                                (bf16)((v + qbv) * 0.18033688f);
                        }
                    }
                }
        }
    }
}

// ---------------------------------------------------------------------------
// MFMA flash attention v8: round-6 memory structure (Es LDS ring from
// swizzled embT, K/V double-buffer, one barrier per k-tile) but 512 threads:
// 8 waves, one 16-row q-chunk each -> 16 waves/CU at 2 blocks/CU (80 KB LDS).
// exp2 softmax (scale folded into Q), ds_permute diagonal gather.
// Grid: (32 bn, 16 qc) with CU-paired qc mapping (constant 34 tiles/pair).
// ---------------------------------------------------------------------------
__global__ __launch_bounds__(512, 4) void attn_kernel(
    const bf16* __restrict__ Qb, const bf16* __restrict__ Kb,
    const bf16* __restrict__ Vtb, const bf16* __restrict__ Eb,
    bf16* __restrict__ o)
{
    __shared__ __align__(16) bf16 Ks[2][4096];    // 16 KB
    __shared__ __align__(16) bf16 Vts[2][4096];   // 16 KB
    __shared__ __align__(16) bf16 Es[256 * 64];   // 32 KB ring
    __shared__ __align__(16) bf16 PS[8 * 1024];   // 16 KB, chunk-swizzled

    const int t    = threadIdx.x;
    const int lane = t & 63;
    const int w    = t >> 6;         // 0..7
    const int quad = lane >> 4;
    const int l16  = lane & 15;

    const int bx = blockIdx.x;
    const int b  = bx >> 4, n = bx & 15;
    const int yy = blockIdx.y;
    const int qc = (yy < 8) ? (15 - 2 * yy) : (2 * yy - 16);
    const int q0 = qc * 128;
    const int KT = 2 * qc + 2;
    const int qw = q0 + 16 * w;      // this wave's 16 q-rows

    const bf16* __restrict__ Qp = Qb  + (size_t)bx * SEQ * 64;
    const bf16* __restrict__ Kp = Kb  + (size_t)bx * SEQ * 64;
    const bf16* __restrict__ Vp = Vtb + (size_t)bx * SEQ * 64;
    const bf16* __restrict__ Ep = Eb  + (size_t)n  * SEQ * 64;

    const int key8 = (l16 & 7) << 3;
    const int ec0  = ((quad * 8) ^ key8) * 2;        // byte offset in 128B row
    const int ec1  = ((32 + quad * 8) ^ key8) * 2;

    // Q fragments (plain layout)
    bf16x8 qf0 = *(const bf16x8*)(Qp + (size_t)(qw + l16) * 64 + quad * 8);
    bf16x8 qf1 = *(const bf16x8*)(Qp + (size_t)(qw + l16) * 64 + 32 + quad * 8);

    // pos push-permute setup
    int dsta[4];
    bool condp[4];
#pragma unroll
    for (int rg = 0; rg < 4; ++rg) {
        int rr   = quad * 4 + rg;
        int l16c = (rr + 15 - l16) & 15;
        dsta[rg]  = ((lane & 48) + l16c) << 2;
        condp[rg] = rr > l16c;
    }

    f32x4 O[4] = {};
    float lsum[4] = {0.f, 0.f, 0.f, 0.f};

    // preload K/V tile 0 (8 KB each, one gload per) + 192-row E window
    {
        gload16(Kp + t * 8, (char*)Ks[0] + t * 16);
        gload16(Vp + (size_t)(t >> 3) * SEQ + (t & 7) * 8, (char*)Vts[0] + t * 16);
        const long D0 = (long)q0 - 63;
#pragma unroll
        for (int g = 0; g < 3; ++g)
            gload16(Ep + D0 * 64 + g * 4096 + t * 8, (char*)Es + g * 8192 + t * 16);
    }

    for (int kt = 0; kt < KT; ++kt) {
        const int k0 = kt * 64;
        __syncthreads();

        const int nt = kt + 1;
        if (nt < KT) {   // prefetch next tile (overlaps this tile's compute)
            gload16(Kp + nt * 4096 + t * 8, (char*)Ks[nt & 1] + t * 16);
            gload16(Vp + (size_t)(t >> 3) * SEQ + nt * 64 + (t & 7) * 8,
                    (char*)Vts[nt & 1] + t * 16);
            const long d0 = (long)q0 - nt * 64 - 63;
            const int rI = (-64 * nt) & 255;
            gload16(Ep + d0 * 64 + t * 8, (char*)Es + rI * 128 + t * 16);
        }

        if (k0 <= qw + 15) {   // wave fully masked otherwise
            // pos band: 5 subtiles from ring
            f32x4 pa[5];
            const int rb = 16 * w - k0;
#pragma unroll
            for (int jj = 0; jj < 5; ++jj) {
                const char* ep = (const char*)Es + ((rb + 16 * jj + l16) & 255) * 128;
                bf16x8 e0 = *(const bf16x8*)(ep + ec0);
                bf16x8 e1 = *(const bf16x8*)(ep + ec1);
                f32x4 a = {0, 0, 0, 0};
                a = __builtin_amdgcn_mfma_f32_16x16x32_bf16(qf1, e1, a, 0, 0, 0);
                a = __builtin_amdgcn_mfma_f32_16x16x32_bf16(qf0, e0, a, 0, 0, 0);
                pa[jj] = a;
            }

            // content scores
            const char* kb = (const char*)Ks[kt & 1];
            f32x4 S[4];
#pragma unroll
            for (int j = 0; j < 4; ++j) {
                const char* kp = kb + (j * 16 + l16) * 128;
                bf16x8 kf0 = *(const bf16x8*)(kp + ec0);
                bf16x8 kf1 = *(const bf16x8*)(kp + ec1);
                f32x4 a = {0, 0, 0, 0};
                a = __builtin_amdgcn_mfma_f32_16x16x32_bf16(qf1, kf1, a, 0, 0, 0);
                a = __builtin_amdgcn_mfma_f32_16x16x32_bf16(qf0, kf0, a, 0, 0, 0);
                S[j] = a;
            }

            // diagonal gather + mask + exp2 (no-max softmax)
#pragma unroll
            for (int j = 0; j < 4; ++j) {
#pragma unroll
                for (int rg = 0; rg < 4; ++rg) {
                    float vsel = condp[rg] ? pa[4 - j][rg] : pa[3 - j][rg];
                    int pv = __builtin_amdgcn_ds_permute(dsta[rg], __float_as_int(vsel));
                    float sv = S[j][rg] + __int_as_float(pv);
                    bool valid = (k0 + j * 16 + l16) <= (qw + quad * 4 + rg);
                    S[j][rg] = valid ? exp2f(sv) : 0.0f;
                }
            }
#pragma unroll
            for (int rg = 0; rg < 4; ++rg)
                lsum[rg] += S[0][rg] + S[1][rg] + S[2][rg] + S[3][rg];

            // P -> LDS (wave-private, chunk-swizzled) -> A-frags
#pragma unroll
            for (int j = 0; j < 4; ++j)
#pragma unroll
                for (int rg = 0; rg < 4; ++rg) {
                    int r = quad * 4 + rg, c = j * 16 + l16;
                    PS[w * 1024 + r * 64 + (c ^ ((r & 7) << 3))] = (bf16)S[j][rg];
                }
            bf16x8 pf0 = *(const bf16x8*)(PS + w * 1024 + l16 * 64 + ((quad * 8) ^ key8));
            bf16x8 pf1 = *(const bf16x8*)(PS + w * 1024 + l16 * 64 + ((32 + quad * 8) ^ key8));

            // PV
            const char* vb = (const char*)Vts[kt & 1];
#pragma unroll
            for (int j4 = 0; j4 < 4; ++j4) {
                const char* vp = vb + (j4 * 16 + l16) * 128;
                bf16x8 v0 = *(const bf16x8*)(vp + ec0);
                bf16x8 v1 = *(const bf16x8*)(vp + ec1);
                O[j4] = __builtin_amdgcn_mfma_f32_16x16x32_bf16(pf1, v1, O[j4], 0, 0, 0);
                O[j4] = __builtin_amdgcn_mfma_f32_16x16x32_bf16(pf0, v0, O[j4], 0, 0, 0);
            }
        }
    }

    // epilogue: reduce row-sums, normalize, write bf16
#pragma unroll
    for (int rg = 0; rg < 4; ++rg) {
        float s = lsum[rg];
        s += __shfl_xor(s, 1);
        s += __shfl_xor(s, 2);
        s += __shfl_xor(s, 4);
        s += __shfl_xor(s, 8);
        float inv = 1.0f / s;
        int q = qw + quad * 4 + rg;
        size_t ro = ((size_t)(b * SEQ + q)) * NH + n * 64;
        o[ro +  0 + l16] = (bf16)(O[0][rg] * inv);
        o[ro + 16 + l16] = (bf16)(O[1][rg] * inv);
        o[ro + 32 + l16] = (bf16)(O[2][rg] * inv);
        o[ro + 48 + l16] = (bf16)(O[3][rg] * inv);
    }
}

// ---------------------------------------------------------------------------
extern "C" void kernel_launch(void* const* d_in, const int* in_sizes, int n_in,
                              void* d_out, int out_size, void* d_ws, size_t ws_size,
                              hipStream_t stream) {
    const float* inp        = (const float*)d_in[0];
    const float* qkv_w      = (const float*)d_in[1];
    const float* q_bias     = (const float*)d_in[2];
    const float* positional = (const float*)d_in[3];
    const float* out_kernel = (const float*)d_in[4];
    const float* out_bias   = (const float*)d_in[5];

    char* p = (char*)d_ws;
    auto alloc = [&](size_t bytes) {
        char* q = p; p += (bytes + 255) & ~(size_t)255; return q;
    };
    bf16* qbuf    = (bf16*)alloc((size_t)BATCH * HEADS * SEQ * HSIZE * 2);
    bf16* kbuf    = (bf16*)alloc((size_t)BATCH * HEADS * SEQ * HSIZE * 2);
    bf16* vtbuf   = (bf16*)alloc((size_t)BATCH * HEADS * SEQ * HSIZE * 2);
    bf16* embT    = (bf16*)alloc((size_t)HEADS * SEQ * HSIZE * 2);  // after vtbuf (negative-d slack)
    bf16* sins_bf = (bf16*)alloc((size_t)SEQ * FREQS * 2);          // after embT (d>=2048 slack)
    bf16* obuf    = (bf16*)alloc((size_t)BATCH * SEQ * NH * 2);
    bf16* a_bf    = (bf16*)alloc((size_t)BATCH * SEQ * DMODEL * 2);
    bf16* wt_qkv  = (bf16*)alloc((size_t)QKVN * DMODEL * 2);
    bf16* wt_out  = (bf16*)alloc((size_t)NH * DMODEL * 2);
    bf16* wt_pos  = (bf16*)alloc((size_t)NH * FREQS * 2);

    const float qkv_scale = (float)pow(3.0 * DMODEL * HSIZE * HEADS, -0.25);
    const float emb_scale = 0.0625f;   // 256^-0.5
    const float out_scale = 0.03125f;  // (1024*1024)^-0.25

    // 1. merged prep
    prep_kernel<<<8480, 256, 0, stream>>>(
        inp, qkv_w, out_kernel, positional, a_bf, wt_qkv, wt_out, wt_pos, sins_bf);

    // 2. merged QKV projection + emb GEMM
    mfma_gemm<1><<<dim3(32, 32), 256, 0, stream>>>(
        a_bf, wt_qkv, DMODEL, qkv_scale, q_bias, nullptr, qbuf, kbuf, vtbuf,
        sins_bf, wt_pos, embT, emb_scale);

    // 3. flash attention (512 blocks x 512 threads)
    attn_kernel<<<dim3(32, 16), 512, 0, stream>>>(
        qbuf, kbuf, vtbuf, embT, obuf);

    // 4. output projection (fp32 out)
    mfma_gemm<0><<<dim3(8, 32), 256, 0, stream>>>(
        obuf, wt_out, DMODEL, out_scale, out_bias, (float*)d_out,
        nullptr, nullptr, nullptr, nullptr, nullptr, nullptr, 0.0f);
}